// Round 4
// baseline (177.725 us; speedup 1.0000x reference)
//
#include <hip/hip_runtime.h>
#include <hip/hip_bf16.h>

#define A_DIM 200
#define F_DIM 53
#define NAF 38
#define NPHYS 15
#define R_OUT 20
#define C_OUT 1024
#define BLOCK 256
#define HPAD 40      // ushort stride of s_h rows (k 0..31 used, 20..31 zero)
#define MROWS 224    // 7 tiles of 32
#define KP 24        // wcT k-stride (k>=20 zeroed)

typedef __attribute__((ext_vector_type(8))) short short8;
typedef __attribute__((ext_vector_type(16))) float floatx16;

__device__ __forceinline__ float bf2f(ushort u) { return __uint_as_float((uint)u << 16); }
__device__ __forceinline__ ushort f2bf(float f) {
    union { __hip_bfloat16 h; ushort u; } cv; cv.h = __float2bfloat16(f); return cv.u;
}

// Wc (20,1024) fp32 -> wcT (1024,24) bf16, k>=20 zeroed
__global__ void wc_prep(const float* __restrict__ Wc, ushort* __restrict__ wcT) {
    const int i = blockIdx.x * 256 + threadIdx.x;
    if (i >= C_OUT * KP) return;
    const int col = i / KP, k = i - col * KP;
    wcT[i] = f2bf((k < R_OUT) ? Wc[k * C_OUT + col] : 0.f);
}

template <bool USE_WS>
__global__ __launch_bounds__(BLOCK, 4) void pggcn_kernel(
    const float* __restrict__ inputs,
    const int*   __restrict__ i_s,
    const float* __restrict__ W_self,
    const float* __restrict__ W_nei,
    const float* __restrict__ b_r,
    const float* __restrict__ Wc,
    const float* __restrict__ bc,
    const float* __restrict__ W1,
    const float* __restrict__ b1,
    const float* __restrict__ W5,
    const float* __restrict__ b5,
    const float* __restrict__ W6,
    const float* __restrict__ b6,
    const float* __restrict__ W7,
    const float* __restrict__ b7,
    const ushort* __restrict__ wcT,
    float* __restrict__ out)
{
    __shared__ __align__(16) ushort s_h[MROWS * HPAD];   // 17920 B
    __shared__ float s_neip[4 * 32];
    __shared__ float s_hnei[32];
    __shared__ float s_phys[NPHYS];

    // aliases into s_h (dead after main MFMA loop)
    float* s_pool = (float*)s_h;                 // 1024 f
    float* s_red  = (float*)s_h + C_OUT;         // 256 f
    float* s_d1   = (float*)s_h + C_OUT + 256;   // 32 f
    float* s_d5   = (float*)s_h + C_OUT + 288;   // 16 f

    const int b    = blockIdx.x;
    const int t    = threadIdx.x;
    const int lane = t & 63;
    const int wv   = t >> 6;
    const int col  = lane & 31;   // M-row for A-frags, N-col for B/C-frags
    const int hi   = lane >> 5;
    const int wb   = wv * 256;
    const int ns   = i_s[b];
    const float* in_b = inputs + (size_t)b * (A_DIM * F_DIM);

    if (t < NPHYS) s_phys[t] = in_b[NAF + t];

    // ---- W_self / W_nei B-frags (48x32, 3 k-steps), scalar L2 gather ----
    short8 bws[3], bwn[3];
    #pragma unroll
    for (int ks = 0; ks < 3; ++ks) {
        #pragma unroll
        for (int j = 0; j < 8; ++j) {
            const int k = ks * 16 + hi * 8 + j;
            const bool p = (col < R_OUT) && (k < NAF);
            bws[ks][j] = (short)(p ? f2bf(W_self[k * R_OUT + col]) : 0);
            bwn[ks][j] = (short)(p ? f2bf(W_nei [k * R_OUT + col]) : 0);
        }
    }

    // ---- h-MFMA: D_self = atom@W_self (pre-act -> s_h bf16),
    //      D_nei row-summed -> hnei partials (dead rows zeroed via A) ----
    const int nmt = (ns + 31) >> 5;
    float pnei = 0.f;
    for (int mt = wv; mt < nmt; mt += 4) {
        const int row = mt * 32 + col;
        const float* rp = in_b + (size_t)row * F_DIM;
        const bool v = row < ns;
        short8 a[3];
        #pragma unroll
        for (int ks = 0; ks < 3; ++ks) {
            #pragma unroll
            for (int j = 0; j < 8; ++j) {
                const int k = ks * 16 + hi * 8 + j;
                a[ks][j] = (short)((v && k < NAF) ? f2bf(rp[k]) : 0);
            }
        }
        floatx16 aS, aN;
        #pragma unroll
        for (int r = 0; r < 16; ++r) { aS[r] = 0.f; aN[r] = 0.f; }
        #pragma unroll
        for (int ks = 0; ks < 3; ++ks) {
            aS = __builtin_amdgcn_mfma_f32_32x32x16_bf16(a[ks], bws[ks], aS, 0, 0, 0);
            aN = __builtin_amdgcn_mfma_f32_32x32x16_bf16(a[ks], bwn[ks], aN, 0, 0, 0);
        }
        #pragma unroll
        for (int r = 0; r < 16; ++r) {
            const int rr = (r & 3) + 8 * (r >> 2) + 4 * hi;
            s_h[(mt * 32 + rr) * HPAD + col] = f2bf(aS[r]);
            pnei += aN[r];
        }
    }
    pnei += __shfl_xor(pnei, 32);
    if (hi == 0) s_neip[wv * 32 + col] = pnei;
    __syncthreads();

    if (t < 32) {
        float s = 0.f;
        if (t < R_OUT) {
            s = b_r[t];
            #pragma unroll
            for (int w = 0; w < 4; ++w) s += s_neip[w * 32 + t];
        }
        s_hnei[t] = s;
    }
    __syncthreads();

    // ---- main B-frags (Wc 32x32 per nt, 2 k-steps) + bias; issue before
    //      h-finish so L2 latency hides under the LDS pass ----
    short8 bfr0[8], bfr1[8];
    float  bcv[8];
    #pragma unroll
    for (int nt = 0; nt < 8; ++nt) {
        const int c2 = wb + nt * 32 + col;
        bcv[nt] = bc[c2];
        if (USE_WS) {
            bfr0[nt] = *(const short8*)&wcT[c2 * KP + hi * 8];
            if (hi == 0) {
                bfr1[nt] = *(const short8*)&wcT[c2 * KP + 16];
            } else {
                #pragma unroll
                for (int j = 0; j < 8; ++j) bfr1[nt][j] = 0;
            }
        } else {
            #pragma unroll
            for (int j = 0; j < 8; ++j) {
                const int k0 = hi * 8 + j;            // < 16 < R_OUT
                bfr0[nt][j] = (short)f2bf(Wc[k0 * C_OUT + c2]);
                const int k1 = 16 + hi * 8 + j;
                bfr1[nt][j] = (short)((k1 < R_OUT) ? f2bf(Wc[k1 * C_OUT + c2]) : 0);
            }
        }
    }

    // ---- h-finish: h = relu(pre_act + hnei[col]) in place (own tiles) ----
    for (int mt = wv; mt < nmt; mt += 4) {
        #pragma unroll
        for (int r = 0; r < 16; ++r) {
            const int rr = (r & 3) + 8 * (r >> 2) + 4 * hi;
            const int idx = (mt * 32 + rr) * HPAD + col;
            s_h[idx] = f2bf(fmaxf(bf2f(s_h[idx]) + s_hnei[col], 0.f));
        }
    }
    __syncthreads();

    // ---- main: pooled = sum_rows relu(h @ Wc + bc) ----
    float pool[8];
    #pragma unroll
    for (int nt = 0; nt < 8; ++nt) pool[nt] = 0.f;

    for (int mt = 0; mt < nmt; ++mt) {
        const short8 a0 = *(const short8*)&s_h[(mt * 32 + col) * HPAD + hi * 8];
        const short8 a1 = *(const short8*)&s_h[(mt * 32 + col) * HPAD + 16 + hi * 8];
        const bool full = (mt * 32 + 32 <= ns);
        #pragma unroll
        for (int nt = 0; nt < 8; ++nt) {
            floatx16 acc;
            #pragma unroll
            for (int r = 0; r < 16; ++r) acc[r] = bcv[nt];
            acc = __builtin_amdgcn_mfma_f32_32x32x16_bf16(a0, bfr0[nt], acc, 0, 0, 0);
            acc = __builtin_amdgcn_mfma_f32_32x32x16_bf16(a1, bfr1[nt], acc, 0, 0, 0);
            if (full) {
                #pragma unroll
                for (int r = 0; r < 16; ++r) pool[nt] += fmaxf(acc[r], 0.f);
            } else {
                #pragma unroll
                for (int r = 0; r < 16; ++r) {
                    const int rr = mt * 32 + (r & 3) + 8 * (r >> 2) + 4 * hi;
                    pool[nt] += (rr < ns) ? fmaxf(acc[r], 0.f) : 0.f;
                }
            }
        }
    }
    #pragma unroll
    for (int nt = 0; nt < 8; ++nt) {
        float p = pool[nt];
        p += __shfl_xor(p, 32);
        pool[nt] = p;
    }
    __syncthreads();   // s_h dead; alias region safe
    if (hi == 0) {
        #pragma unroll
        for (int nt = 0; nt < 8; ++nt) s_pool[wb + nt * 32 + col] = pool[nt];
    }
    __syncthreads();

    // ---- d1 = relu(pooled @ W1 + b1) ----
    {
        const int m = t & 31, part = t >> 5;
        float s = 0.f;
        const int j0 = part * 128;
        for (int j = j0; j < j0 + 128; ++j) s += s_pool[j] * W1[j * 32 + m];
        s_red[part * 32 + m] = s;
    }
    __syncthreads();
    if (t < 32) {
        float s = b1[t];
        #pragma unroll
        for (int p = 0; p < 8; ++p) s += s_red[p * 32 + t];
        s_d1[t] = fmaxf(s, 0.f);
    }
    __syncthreads();

    // ---- d5 = relu(d1 @ W5 + b5) ----
    if (t < 16) {
        float s = b5[t];
        #pragma unroll
        for (int m = 0; m < 32; ++m) s += s_d1[m] * W5[m * 16 + t];
        s_d5[t] = fmaxf(s, 0.f);
    }
    __syncthreads();

    // ---- model_var, merge, output ----
    if (t == 0) {
        float mv = b6[0];
        #pragma unroll
        for (int m = 0; m < 16; ++m) mv += s_d5[m] * W6[m];
        float o = b7[0] + W7[0] * mv;
        #pragma unroll
        for (int i = 0; i < NPHYS; ++i) o += W7[i + 1] * s_phys[i];
        out[(size_t)b * 16] = o;
    }
    if (t < NPHYS) out[(size_t)b * 16 + 1 + t] = s_phys[t];
}

extern "C" void kernel_launch(void* const* d_in, const int* in_sizes, int n_in,
                              void* d_out, int out_size, void* d_ws, size_t ws_size,
                              hipStream_t stream) {
    const float* inputs = (const float*)d_in[0];
    const int*   i_s    = (const int*)d_in[1];
    const float* W_self = (const float*)d_in[2];
    const float* W_nei  = (const float*)d_in[3];
    const float* b_r    = (const float*)d_in[4];
    const float* Wc     = (const float*)d_in[5];
    const float* bc     = (const float*)d_in[6];
    const float* W1     = (const float*)d_in[7];
    const float* b1     = (const float*)d_in[8];
    const float* W5     = (const float*)d_in[9];
    const float* b5     = (const float*)d_in[10];
    const float* W6     = (const float*)d_in[11];
    const float* b6     = (const float*)d_in[12];
    const float* W7     = (const float*)d_in[13];
    const float* b7     = (const float*)d_in[14];
    float* out = (float*)d_out;

    const int B = in_sizes[1];   // 1024
    const bool use_ws = (ws_size >= (size_t)(C_OUT * KP * sizeof(ushort)));
    ushort* wcT = (ushort*)d_ws;

    if (use_ws) {
        wc_prep<<<(C_OUT * KP + 255) / 256, 256, 0, stream>>>(Wc, wcT);
        pggcn_kernel<true><<<B, BLOCK, 0, stream>>>(inputs, i_s, W_self, W_nei, b_r,
            Wc, bc, W1, b1, W5, b5, W6, b6, W7, b7, wcT, out);
    } else {
        pggcn_kernel<false><<<B, BLOCK, 0, stream>>>(inputs, i_s, W_self, W_nei, b_r,
            Wc, bc, W1, b1, W5, b5, W6, b6, W7, b7, wcT, out);
    }
}

// Round 6
// 65.164 us; speedup vs baseline: 2.7273x; 2.7273x over previous
//
#include <hip/hip_runtime.h>
#include <hip/hip_bf16.h>

#define A_DIM 200
#define F_DIM 53
#define NAF 38
#define NPHYS 15
#define R_OUT 20
#define C_OUT 1024
#define BLOCK 256
#define HPAD 40      // s_hb ushort row stride; cols 0..31 used, 32..39 unused
#define MROWS 208
#define KP 24        // wcT k-stride (k>=20 zeroed)

typedef __attribute__((ext_vector_type(8))) short short8;
typedef __attribute__((ext_vector_type(4))) float floatx4;

__device__ __forceinline__ float bf2f(ushort u) { return __uint_as_float((uint)u << 16); }
__device__ __forceinline__ ushort f2bf(float f) {
    union { __hip_bfloat16 h; ushort u; } cv; cv.h = __float2bfloat16(f); return cv.u;
}

// Wc (20,1024) fp32 -> wcT (1024,24) bf16, k>=20 zeroed
__global__ void wc_prep(const float* __restrict__ Wc, ushort* __restrict__ wcT) {
    const int i = blockIdx.x * 256 + threadIdx.x;
    if (i >= C_OUT * KP) return;
    const int col = i / KP, k = i - col * KP;
    wcT[i] = f2bf((k < R_OUT) ? Wc[k * C_OUT + col] : 0.f);
}

template <bool USE_WS>
__global__ __launch_bounds__(BLOCK, 4) void pggcn_kernel(
    const float* __restrict__ inputs,
    const int*   __restrict__ i_s,
    const float* __restrict__ W_self,
    const float* __restrict__ W_nei,
    const float* __restrict__ b_r,
    const float* __restrict__ Wc,
    const float* __restrict__ bc,
    const float* __restrict__ W1,
    const float* __restrict__ b1,
    const float* __restrict__ W5,
    const float* __restrict__ b5,
    const float* __restrict__ W6,
    const float* __restrict__ b6,
    const float* __restrict__ W7,
    const float* __restrict__ b7,
    const ushort* __restrict__ wcT,
    float* __restrict__ out)
{
    __shared__ __align__(16) ushort s_hb[MROWS * HPAD];   // 16640 B (atoms -> h, in place)
    __shared__ __align__(16) ushort s_rem[MROWS * 8];     // 3328 B (atom k 32..39, 38/39 zero)
    __shared__ float s_neip[4 * 32];
    __shared__ float s_hnei[32];
    __shared__ float s_phys[NPHYS];

    // aliases into s_hb (dead after main loop)
    float* s_pool = (float*)s_hb;
    float* s_red  = (float*)s_hb + C_OUT;
    float* s_d1   = (float*)s_hb + C_OUT + 256;
    float* s_d5   = (float*)s_hb + C_OUT + 288;

    const int b    = blockIdx.x;
    const int t    = threadIdx.x;
    const int lane = t & 63;
    const int wv   = t >> 6;
    const int lr   = lane & 15;
    const int lg   = lane >> 4;
    const int wb   = wv * 256;
    const int ns   = i_s[b];
    const int nmt  = (ns + 15) >> 4;
    const float* in_b = inputs + (size_t)b * (A_DIM * F_DIM);

    // ---- W_self/W_nei B-frags (2 n-tiles x 2 k-steps), issued first ----
    // B layout: col = lane&15, k = (lane>>4)*8 + j
    short8 bws0[2], bws1[2], bwn0[2], bwn1[2];
    #pragma unroll
    for (int nt = 0; nt < 2; ++nt) {
        const int c = nt * 16 + lr;
        const bool cv_ = (c < R_OUT);
        #pragma unroll
        for (int j = 0; j < 8; ++j) {
            const int k0 = lg * 8 + j;         // 0..31 (< NAF always)
            const int k1 = 32 + lg * 8 + j;    // 32..63
            bws0[nt][j] = (short)(cv_ ? f2bf(W_self[k0 * R_OUT + c]) : 0);
            bwn0[nt][j] = (short)(cv_ ? f2bf(W_nei [k0 * R_OUT + c]) : 0);
            bws1[nt][j] = (short)((cv_ && k1 < NAF) ? f2bf(W_self[k1 * R_OUT + c]) : 0);
            bwn1[nt][j] = (short)((cv_ && k1 < NAF) ? f2bf(W_nei [k1 * R_OUT + c]) : 0);
        }
    }

    if (t < NPHYS) s_phys[t] = in_b[NAF + t];

    // ---- stage atoms bf16, 40 elems/row: 0..31 -> s_hb, 32..39 -> s_rem ----
    // (f>=NAF zeroed; rows >= ns zeroed to the tile boundary)
    const int tot = nmt * 16 * 40;
    for (int i = t; i < tot; i += BLOCK) {
        const int r = i / 40;
        const int f = i - r * 40;
        const float v = (r < ns && f < NAF) ? in_b[r * F_DIM + f] : 0.f;
        if (f < 32) s_hb[r * HPAD + f] = f2bf(v);
        else        s_rem[r * 8 + (f - 32)] = f2bf(v);
    }
    __syncthreads();

    // ---- h-MFMA: preact_self -> s_hb (in place), nei row-sums -> pn ----
    float pn0 = 0.f, pn1 = 0.f;
    for (int mt = wv; mt < nmt; mt += 4) {
        const int ar = mt * 16 + lr;
        const short8 a0 = *(const short8*)&s_hb[ar * HPAD + lg * 8];
        short8 a1 = short8{0, 0, 0, 0, 0, 0, 0, 0};
        if (lg == 0) a1 = *(const short8*)&s_rem[ar * 8];
        floatx4 aS0 = {0.f, 0.f, 0.f, 0.f}, aS1 = {0.f, 0.f, 0.f, 0.f};
        floatx4 aN0 = {0.f, 0.f, 0.f, 0.f}, aN1 = {0.f, 0.f, 0.f, 0.f};
        aS0 = __builtin_amdgcn_mfma_f32_16x16x32_bf16(a0, bws0[0], aS0, 0, 0, 0);
        aS0 = __builtin_amdgcn_mfma_f32_16x16x32_bf16(a1, bws1[0], aS0, 0, 0, 0);
        aS1 = __builtin_amdgcn_mfma_f32_16x16x32_bf16(a0, bws0[1], aS1, 0, 0, 0);
        aS1 = __builtin_amdgcn_mfma_f32_16x16x32_bf16(a1, bws1[1], aS1, 0, 0, 0);
        aN0 = __builtin_amdgcn_mfma_f32_16x16x32_bf16(a0, bwn0[0], aN0, 0, 0, 0);
        aN0 = __builtin_amdgcn_mfma_f32_16x16x32_bf16(a1, bwn1[0], aN0, 0, 0, 0);
        aN1 = __builtin_amdgcn_mfma_f32_16x16x32_bf16(a0, bwn0[1], aN1, 0, 0, 0);
        aN1 = __builtin_amdgcn_mfma_f32_16x16x32_bf16(a1, bwn1[1], aN1, 0, 0, 0);
        // C/D layout: col = lane&15, row = (lane>>4)*4 + q
        #pragma unroll
        for (int q = 0; q < 4; ++q) {
            const int row = mt * 16 + lg * 4 + q;
            s_hb[row * HPAD + lr]      = f2bf(aS0[q]);
            s_hb[row * HPAD + 16 + lr] = f2bf(aS1[q]);
            pn0 += aN0[q];
            pn1 += aN1[q];
        }
    }
    pn0 += __shfl_xor(pn0, 16); pn0 += __shfl_xor(pn0, 32);
    pn1 += __shfl_xor(pn1, 16); pn1 += __shfl_xor(pn1, 32);
    if (lg == 0) {
        s_neip[wv * 32 + lr]      = pn0;
        s_neip[wv * 32 + 16 + lr] = pn1;
    }
    __syncthreads();

    if (t < 32) {
        float s = 0.f;
        if (t < R_OUT) {
            s = b_r[t];
            #pragma unroll
            for (int w = 0; w < 4; ++w) s += s_neip[w * 32 + t];
        }
        s_hnei[t] = s;
    }
    __syncthreads();

    // ---- h-finish in place: h = (row<ns) ? relu(preact + hnei) : 0 ----
    for (int mt = wv; mt < nmt; mt += 4) {
        #pragma unroll
        for (int q = 0; q < 4; ++q) {
            const int row = mt * 16 + lg * 4 + q;
            const bool v = (row < ns);
            const int i0 = row * HPAD + lr;
            const float h0 = bf2f(s_hb[i0])      + s_hnei[lr];
            const float h1 = bf2f(s_hb[i0 + 16]) + s_hnei[16 + lr];
            s_hb[i0]      = v ? f2bf(fmaxf(h0, 0.f)) : (ushort)0;
            s_hb[i0 + 16] = v ? f2bf(fmaxf(h1, 0.f)) : (ushort)0;
        }
    }
    __syncthreads();

    // ---- main: pooled = sum_rows relu(h @ Wc + bc); dead rows corrected ----
    const float dead = (float)(nmt * 16 - ns);
    float pool[16];
    #pragma unroll
    for (int nt = 0; nt < 16; ++nt) pool[nt] = 0.f;

    #pragma unroll 1
    for (int half = 0; half < 2; ++half) {
        short8 bfr[8];
        float  bcv[8];
        #pragma unroll
        for (int q8 = 0; q8 < 8; ++q8) {
            const int col = wb + (half * 8 + q8) * 16 + lr;
            bcv[q8] = bc[col];
            if (USE_WS) {
                if (lg < 3) bfr[q8] = *(const short8*)&wcT[col * KP + lg * 8];
                else        bfr[q8] = short8{0, 0, 0, 0, 0, 0, 0, 0};
            } else {
                #pragma unroll
                for (int j = 0; j < 8; ++j) {
                    const int k = lg * 8 + j;
                    bfr[q8][j] = (short)((k < R_OUT) ? f2bf(Wc[k * C_OUT + col]) : 0);
                }
            }
        }
        for (int mt = 0; mt < nmt; ++mt) {
            const short8 af = *(const short8*)&s_hb[(mt * 16 + lr) * HPAD + lg * 8];
            #pragma unroll
            for (int q8 = 0; q8 < 8; ++q8) {
                floatx4 acc = { bcv[q8], bcv[q8], bcv[q8], bcv[q8] };
                acc = __builtin_amdgcn_mfma_f32_16x16x32_bf16(af, bfr[q8], acc, 0, 0, 0);
                pool[half * 8 + q8] += fmaxf(acc[0], 0.f) + fmaxf(acc[1], 0.f)
                                     + fmaxf(acc[2], 0.f) + fmaxf(acc[3], 0.f);
            }
        }
        // exact dead-row correction, once per column (lg==0 lanes only)
        if (lg == 0) {
            #pragma unroll
            for (int q8 = 0; q8 < 8; ++q8)
                pool[half * 8 + q8] -= dead * fmaxf(bcv[q8], 0.f);
        }
    }

    #pragma unroll
    for (int nt = 0; nt < 16; ++nt) {
        float p = pool[nt];
        p += __shfl_xor(p, 16);
        p += __shfl_xor(p, 32);
        pool[nt] = p;
    }
    __syncthreads();   // all s_hb reads done; alias region safe
    if (lg == 0) {
        #pragma unroll
        for (int nt = 0; nt < 16; ++nt) s_pool[wb + nt * 16 + lr] = pool[nt];
    }
    __syncthreads();

    // ---- d1 = relu(pooled @ W1 + b1) ----
    {
        const int m = t & 31, part = t >> 5;
        float s = 0.f;
        const int j0 = part * 128;
        for (int j = j0; j < j0 + 128; ++j) s += s_pool[j] * W1[j * 32 + m];
        s_red[part * 32 + m] = s;
    }
    __syncthreads();
    if (t < 32) {
        float s = b1[t];
        #pragma unroll
        for (int p = 0; p < 8; ++p) s += s_red[p * 32 + t];
        s_d1[t] = fmaxf(s, 0.f);
    }
    __syncthreads();

    // ---- d5 = relu(d1 @ W5 + b5) ----
    if (t < 16) {
        float s = b5[t];
        #pragma unroll
        for (int m = 0; m < 32; ++m) s += s_d1[m] * W5[m * 16 + t];
        s_d5[t] = fmaxf(s, 0.f);
    }
    __syncthreads();

    // ---- model_var, merge, output ----
    if (t == 0) {
        float mv = b6[0];
        #pragma unroll
        for (int m = 0; m < 16; ++m) mv += s_d5[m] * W6[m];
        float o = b7[0] + W7[0] * mv;
        #pragma unroll
        for (int i = 0; i < NPHYS; ++i) o += W7[i + 1] * s_phys[i];
        out[(size_t)b * 16] = o;
    }
    if (t < NPHYS) out[(size_t)b * 16 + 1 + t] = s_phys[t];
}

extern "C" void kernel_launch(void* const* d_in, const int* in_sizes, int n_in,
                              void* d_out, int out_size, void* d_ws, size_t ws_size,
                              hipStream_t stream) {
    const float* inputs = (const float*)d_in[0];
    const int*   i_s    = (const int*)d_in[1];
    const float* W_self = (const float*)d_in[2];
    const float* W_nei  = (const float*)d_in[3];
    const float* b_r    = (const float*)d_in[4];
    const float* Wc     = (const float*)d_in[5];
    const float* bc     = (const float*)d_in[6];
    const float* W1     = (const float*)d_in[7];
    const float* b1     = (const float*)d_in[8];
    const float* W5     = (const float*)d_in[9];
    const float* b5     = (const float*)d_in[10];
    const float* W6     = (const float*)d_in[11];
    const float* b6     = (const float*)d_in[12];
    const float* W7     = (const float*)d_in[13];
    const float* b7     = (const float*)d_in[14];
    float* out = (float*)d_out;

    const int B = in_sizes[1];   // 1024
    const bool use_ws = (ws_size >= (size_t)(C_OUT * KP * sizeof(ushort)));
    ushort* wcT = (ushort*)d_ws;

    if (use_ws) {
        wc_prep<<<(C_OUT * KP + 255) / 256, 256, 0, stream>>>(Wc, wcT);
        pggcn_kernel<true><<<B, BLOCK, 0, stream>>>(inputs, i_s, W_self, W_nei, b_r,
            Wc, bc, W1, b1, W5, b5, W6, b6, W7, b7, wcT, out);
    } else {
        pggcn_kernel<false><<<B, BLOCK, 0, stream>>>(inputs, i_s, W_self, W_nei, b_r,
            Wc, bc, W1, b1, W5, b5, W6, b6, W7, b7, wcT, out);
    }
}